// Round 1
// baseline (1517.962 us; speedup 1.0000x reference)
//
#include <hip/hip_runtime.h>
#include <hip/hip_bf16.h>
#include <cstdint>
#include <cstddef>

#define Bn 64
#define Tn 50
#define Pn 49
#define En 512
#define Hn 512
#define Vn 10000
#define IEn 1024
#define G5 2560   // 5*H

__device__ __forceinline__ float sigm(float x)  { return 1.0f / (1.0f + __expf(-x)); }
__device__ __forceinline__ float tanh_f(float x){ return 1.0f - 2.0f / (1.0f + __expf(2.0f * x)); }

// ---------------------------------------------------------------------------
// Generic fp32 tiled GEMM: C[M,N] = A[M,K] @ B[K,N] (+bias) (+rowadd)
// BM=BN=64, BK=16, 256 threads, 4x4 per thread.
// gridDim.z > 1 => split-K partial mode: koff = z*K, C += z*M*N, raw partials.
// GATHER: A row index comes from gidx (A = emb table, row = gidx[m]).
// ---------------------------------------------------------------------------
template<bool GATHER>
__global__ __launch_bounds__(256)
void gemm64(const float* __restrict__ A, int lda,
            const float* __restrict__ B,
            float* __restrict__ C,
            int M, int N, int K,
            const float* __restrict__ bias,
            const float* __restrict__ rowadd, int rowDiv, long rowStride,
            const int* __restrict__ gidx)
{
    const int n0 = blockIdx.x * 64;
    const int m0 = blockIdx.y * 64;
    const long koff = (long)blockIdx.z * K;
    const float* Bp = B + koff * N;
    float* Cp = C + (gridDim.z > 1 ? (size_t)blockIdx.z * (size_t)M * (size_t)N : (size_t)0);

    __shared__ float As[16][64];
    __shared__ float Bs[16][64];

    const int tid = threadIdx.x;
    const int tx = tid & 15;
    const int ty = tid >> 4;
    const int ra = tid >> 2;          // A-load row within tile
    const int ca = (tid & 3) << 2;    // A-load col group (0,4,8,12)

    long arow = GATHER ? (long)gidx[m0 + ra] : (long)(m0 + ra);
    const float* Arow = A + arow * (long)lda + koff + ca;

    const int kl = ty;                // B-load k row (0..15)
    const int nb = tx << 2;           // B-load col group
    const int ncol = n0 + nb;

    float acc[4][4] = {{0.f,0.f,0.f,0.f},{0.f,0.f,0.f,0.f},{0.f,0.f,0.f,0.f},{0.f,0.f,0.f,0.f}};

    for (int k0 = 0; k0 < K; k0 += 16) {
        float4 av = *(const float4*)(Arow + k0);
        float4 bv;
        const float* bptr = Bp + (long)(k0 + kl) * N + ncol;
        if (ncol + 3 < N) {
            bv = *(const float4*)bptr;
        } else {
            bv.x = (ncol + 0 < N) ? bptr[0] : 0.f;
            bv.y = (ncol + 1 < N) ? bptr[1] : 0.f;
            bv.z = (ncol + 2 < N) ? bptr[2] : 0.f;
            bv.w = (ncol + 3 < N) ? bptr[3] : 0.f;
        }
        __syncthreads();
        As[ca + 0][ra] = av.x; As[ca + 1][ra] = av.y;
        As[ca + 2][ra] = av.z; As[ca + 3][ra] = av.w;
        *(float4*)&Bs[kl][nb] = bv;
        __syncthreads();
        #pragma unroll
        for (int kk = 0; kk < 16; kk++) {
            const float4 a = *(const float4*)&As[kk][ty << 2];
            const float4 b = *(const float4*)&Bs[kk][tx << 2];
            const float a_[4] = {a.x, a.y, a.z, a.w};
            const float b_[4] = {b.x, b.y, b.z, b.w};
            #pragma unroll
            for (int i = 0; i < 4; i++)
                #pragma unroll
                for (int j = 0; j < 4; j++)
                    acc[i][j] = fmaf(a_[i], b_[j], acc[i][j]);
        }
    }

    #pragma unroll
    for (int i = 0; i < 4; i++) {
        const int rr = m0 + (ty << 2) + i;
        #pragma unroll
        for (int j = 0; j < 4; j++) {
            const int cc = n0 + (tx << 2) + j;
            if (cc < N) {
                float v = acc[i][j];
                if (bias)   v += bias[cc];
                if (rowadd) v += rowadd[(long)(rr / rowDiv) * rowStride + cc];
                Cp[(long)rr * N + cc] = v;
            }
        }
    }
}

// vg[b,e] = mean_p vproj[b,p,e]
__global__ void vg_mean(const float* __restrict__ vproj, float* __restrict__ vg)
{
    const int tid = blockIdx.x * 256 + threadIdx.x;   // 0..32767
    const int b = tid >> 9, e = tid & 511;
    const float* p = vproj + (long)b * Pn * En + e;
    float s = 0.f;
    #pragma unroll 7
    for (int q = 0; q < Pn; q++) s += p[q * En];
    vg[tid] = s * (1.0f / 49.0f);
}

// h0 = vg@Wh + bh ; m0 = vg@Wm + bm  (64 blocks x 512 threads)
__global__ void h0m0(const float* __restrict__ vg,
                     const float* __restrict__ Wh, const float* __restrict__ bh,
                     const float* __restrict__ Wm, const float* __restrict__ bm,
                     float* __restrict__ h, float* __restrict__ m)
{
    __shared__ float vgs[512];
    const int b = blockIdx.x, e = threadIdx.x;
    vgs[e] = vg[b * 512 + e];
    __syncthreads();
    float a1 = bh[e], a2 = bm[e];
    #pragma unroll 8
    for (int k = 0; k < 512; k++) {
        const float x = vgs[k];
        a1 = fmaf(x, Wh[(long)k * 512 + e], a1);
        a2 = fmaf(x, Wm[(long)k * 512 + e], a2);
    }
    h[b * 512 + e] = a1;
    m[b * 512 + e] = a2;
}

// LSTM elementwise update for step t. gates = base[r] + sum of 4 K-split partials.
__global__ void lstm_update(const float* __restrict__ part,
                            const float* __restrict__ base,
                            float* __restrict__ h, float* __restrict__ m,
                            float* __restrict__ Hs, float* __restrict__ Ss, int t)
{
    const int tid = blockIdx.x * blockDim.x + threadIdx.x;  // 0..32767
    const int b = tid >> 9, e = tid & 511;
    const long r = (long)b * Tn + t;
    const float* bs = base + r * G5;
    float gi = bs[e], gf = bs[512 + e], go = bs[1024 + e], gg = bs[1536 + e], g5 = bs[2048 + e];
    const float* pp = part + (long)b * G5;
    #pragma unroll
    for (int s = 0; s < 4; s++) {
        const float* q = pp + (long)s * Bn * G5;
        gi += q[e]; gf += q[512 + e]; go += q[1024 + e]; gg += q[1536 + e]; g5 += q[2048 + e];
    }
    const float i = sigm(gi), f = sigm(gf), o = sigm(go);
    const float mn = fmaf(i, tanh_f(g5), f * m[tid]);
    const float tm = tanh_f(mn);
    const float hh = o * tm;
    const float ss = gg * tm;
    m[tid] = mn;
    h[tid] = hh;
    Hs[r * 512 + e] = hh;
    Ss[r * 512 + e] = ss;
}

// Per-(b,t) adaptive attention: alog[p] = Waz . tanh(slot_p + ps) + baz over 50 slots,
// softmax, c = sum a*[vproj, h], CH = c + h.
__global__ __launch_bounds__(256)
void attn(const float* __restrict__ vproj, const float* __restrict__ pv,
          const float* __restrict__ PH, const float* __restrict__ PS,
          const float* __restrict__ Hs, const float* __restrict__ Waz,
          const float* __restrict__ baz, float* __restrict__ CH)
{
    const int r = blockIdx.x;            // b*50 + t
    const int b = r / Tn;
    const int tid = threadIdx.x;
    const int lane = tid & 63, wid = tid >> 6;

    __shared__ float ps_s[512];
    __shared__ float ph_s[512];
    __shared__ float alog[64];

    for (int i = tid; i < 512; i += 256) {
        ps_s[i] = PS[(long)r * 512 + i];
        ph_s[i] = PH[(long)r * 512 + i];
    }
    __syncthreads();

    const float4 wz0 = *(const float4*)(Waz + lane * 8);
    const float4 wz1 = *(const float4*)(Waz + lane * 8 + 4);
    const float4 q0  = *(const float4*)&ps_s[lane * 8];
    const float4 q1  = *(const float4*)&ps_s[lane * 8 + 4];

    for (int slot = wid; slot < Pn + 1; slot += 4) {
        const float* src = (slot < Pn) ? (pv + ((long)b * Pn + slot) * 512)
                                       : (const float*)ph_s;
        const float4 x0 = *(const float4*)(src + lane * 8);
        const float4 x1 = *(const float4*)(src + lane * 8 + 4);
        float d = 0.f;
        d = fmaf(tanh_f(x0.x + q0.x), wz0.x, d);
        d = fmaf(tanh_f(x0.y + q0.y), wz0.y, d);
        d = fmaf(tanh_f(x0.z + q0.z), wz0.z, d);
        d = fmaf(tanh_f(x0.w + q0.w), wz0.w, d);
        d = fmaf(tanh_f(x1.x + q1.x), wz1.x, d);
        d = fmaf(tanh_f(x1.y + q1.y), wz1.y, d);
        d = fmaf(tanh_f(x1.z + q1.z), wz1.z, d);
        d = fmaf(tanh_f(x1.w + q1.w), wz1.w, d);
        #pragma unroll
        for (int s = 32; s >= 1; s >>= 1) d += __shfl_xor(d, s);
        if (lane == 0) alog[slot] = d + baz[0];
    }
    __syncthreads();

    if (wid == 0) {
        const float v = (lane < Pn + 1) ? alog[lane] : -3.4e38f;
        float mx = v;
        #pragma unroll
        for (int s = 32; s >= 1; s >>= 1) mx = fmaxf(mx, __shfl_xor(mx, s));
        const float ev = (lane < Pn + 1) ? __expf(v - mx) : 0.f;
        float sm = ev;
        #pragma unroll
        for (int s = 32; s >= 1; s >>= 1) sm += __shfl_xor(sm, s);
        if (lane < Pn + 1) alog[lane] = ev / sm;
    }
    __syncthreads();

    const float a49 = alog[Pn];
    for (int e = tid; e < 512; e += 256) {
        const float hval = Hs[(long)r * 512 + e];
        float c = a49 * hval;
        const float* vp = vproj + (long)b * Pn * 512 + e;
        #pragma unroll 7
        for (int q = 0; q < Pn; q++) c = fmaf(alog[q], vp[q * 512], c);
        CH[(long)r * 512 + e] = c + hval;
    }
}

// In-place row softmax over V=10000 + length mask (masked rows -> 0).
__global__ __launch_bounds__(256)
void softmax_mask(float* __restrict__ out, const int* __restrict__ lengths)
{
    const int r = blockIdx.x, b = r / Tn, t = r % Tn;
    float* row = out + (long)r * Vn;
    const int tid = threadIdx.x;
    float4* row4 = (float4*)row;

    if (t >= lengths[b]) {
        const float4 z = {0.f, 0.f, 0.f, 0.f};
        for (int i = tid; i < Vn / 4; i += 256) row4[i] = z;
        return;
    }

    __shared__ float red[4];
    const int lane = tid & 63, wid = tid >> 6;

    float mx = -3.4e38f;
    for (int i = tid; i < Vn / 4; i += 256) {
        const float4 v = row4[i];
        mx = fmaxf(mx, fmaxf(fmaxf(v.x, v.y), fmaxf(v.z, v.w)));
    }
    #pragma unroll
    for (int s = 32; s >= 1; s >>= 1) mx = fmaxf(mx, __shfl_xor(mx, s));
    if (lane == 0) red[wid] = mx;
    __syncthreads();
    mx = fmaxf(fmaxf(red[0], red[1]), fmaxf(red[2], red[3]));

    float sm = 0.f;
    for (int i = tid; i < Vn / 4; i += 256) {
        const float4 v = row4[i];
        sm += __expf(v.x - mx) + __expf(v.y - mx) + __expf(v.z - mx) + __expf(v.w - mx);
    }
    #pragma unroll
    for (int s = 32; s >= 1; s >>= 1) sm += __shfl_xor(sm, s);
    __syncthreads();
    if (lane == 0) red[wid] = sm;
    __syncthreads();
    sm = red[0] + red[1] + red[2] + red[3];
    const float inv = 1.0f / sm;

    for (int i = tid; i < Vn / 4; i += 256) {
        float4 v = row4[i];
        v.x = __expf(v.x - mx) * inv;
        v.y = __expf(v.y - mx) * inv;
        v.z = __expf(v.z - mx) * inv;
        v.w = __expf(v.w - mx) * inv;
        row4[i] = v;
    }
}

extern "C" void kernel_launch(void* const* d_in, const int* in_sizes, int n_in,
                              void* d_out, int out_size, void* d_ws, size_t ws_size,
                              hipStream_t stream)
{
    (void)in_sizes; (void)n_in; (void)out_size; (void)ws_size;
    const float* v   = (const float*)d_in[0];
    const int*   w   = (const int*)  d_in[1];
    const int*   len = (const int*)  d_in[2];
    const float* emb = (const float*)d_in[3];
    const float* Wv  = (const float*)d_in[4];
    const float* bv  = (const float*)d_in[5];
    const float* Wh  = (const float*)d_in[6];
    const float* bh  = (const float*)d_in[7];
    const float* Wm  = (const float*)d_in[8];
    const float* bm  = (const float*)d_in[9];
    const float* Wl  = (const float*)d_in[10];
    const float* bl  = (const float*)d_in[11];
    const float* Wav = (const float*)d_in[12];
    const float* bav = (const float*)d_in[13];
    const float* Wah = (const float*)d_in[14];
    const float* bah = (const float*)d_in[15];
    const float* Was = (const float*)d_in[16];
    const float* bas = (const float*)d_in[17];
    const float* Waz = (const float*)d_in[18];
    const float* baz = (const float*)d_in[19];
    const float* Wp  = (const float*)d_in[20];
    const float* bp  = (const float*)d_in[21];
    float* out = (float*)d_out;

    float* ws    = (float*)d_ws;
    float* vproj = ws;                               // 3136*512
    float* pvb   = vproj + (size_t)3136 * 512;       // 3136*512
    float* vg    = pvb   + (size_t)3136 * 512;       // 64*512
    float* hbuf  = vg    + (size_t)64 * 512;         // 64*512
    float* mbuf  = hbuf  + (size_t)64 * 512;         // 64*512
    float* vgw   = mbuf  + (size_t)64 * 512;         // 64*2560
    float* part  = vgw   + (size_t)64 * G5;          // 4*64*2560
    float* Hs    = part  + (size_t)4 * 64 * G5;      // 3200*512
    float* Ss    = Hs    + (size_t)3200 * 512;       // 3200*512
    float* PHb   = Ss    + (size_t)3200 * 512;       // 3200*512
    float* PSb   = PHb   + (size_t)3200 * 512;       // 3200*512
    float* CH    = PSb   + (size_t)3200 * 512;       // 3200*512

    // 1. vproj = v @ Wv + bv                      [3136,1024]@[1024,512]
    gemm64<false><<<dim3(8, 49, 1), 256, 0, stream>>>(v, IEn, Wv, vproj, 3136, 512, IEn,
                                                      bv, nullptr, 1, 0, nullptr);
    // 2. vg = mean_p vproj
    vg_mean<<<128, 256, 0, stream>>>(vproj, vg);
    // 3. h0, m0
    h0m0<<<64, 512, 0, stream>>>(vg, Wh, bh, Wm, bm, hbuf, mbuf);
    // 4. vgw = vg @ Wl[512:1024] + bl             [64,512]@[512,2560]
    gemm64<false><<<dim3(40, 1, 1), 256, 0, stream>>>(vg, 512, Wl + (size_t)512 * G5, vgw,
                                                      64, G5, 512, bl, nullptr, 1, 0, nullptr);
    // 5. pv = vproj @ Wav + bav                   [3136,512]@[512,512]
    gemm64<false><<<dim3(8, 49, 1), 256, 0, stream>>>(vproj, 512, Wav, pvb, 3136, 512, 512,
                                                      bav, nullptr, 1, 0, nullptr);
    // 6. base = gather(emb,w) @ Wl[0:512] + vgw[b]   -> stored in d_out (dead before logits)
    gemm64<true><<<dim3(40, 50, 1), 256, 0, stream>>>(emb, 512, Wl, out, 3200, G5, 512,
                                                      nullptr, vgw, Tn, G5, w);
    // 7. sequential scan: gates (split-K=4) + LSTM update
    for (int t = 0; t < Tn; t++) {
        gemm64<false><<<dim3(40, 1, 4), 256, 0, stream>>>(hbuf, 512, Wl + (size_t)1024 * G5, part,
                                                          64, G5, 128, nullptr, nullptr, 1, 0, nullptr);
        lstm_update<<<64, 512, 0, stream>>>(part, out, hbuf, mbuf, Hs, Ss, t);
    }
    // 8. PH = Hs@Wah + bah ; PS = Ss@Was + bas
    gemm64<false><<<dim3(8, 50, 1), 256, 0, stream>>>(Hs, 512, Wah, PHb, 3200, 512, 512,
                                                      bah, nullptr, 1, 0, nullptr);
    gemm64<false><<<dim3(8, 50, 1), 256, 0, stream>>>(Ss, 512, Was, PSb, 3200, 512, 512,
                                                      bas, nullptr, 1, 0, nullptr);
    // 9. attention -> CH = c + h
    attn<<<3200, 256, 0, stream>>>(vproj, pvb, PHb, PSb, Hs, Waz, baz, CH);
    // 10. logits = CH @ Wp + bp -> d_out          [3200,512]@[512,10000]
    gemm64<false><<<dim3(157, 50, 1), 256, 0, stream>>>(CH, 512, Wp, out, 3200, Vn, 512,
                                                        bp, nullptr, 1, 0, nullptr);
    // 11. softmax + mask
    softmax_mask<<<3200, 256, 0, stream>>>(out, len);
}

// Round 2
// 1041.480 us; speedup vs baseline: 1.4575x; 1.4575x over previous
//
#include <hip/hip_runtime.h>
#include <hip/hip_bf16.h>
#include <cstdint>
#include <cstddef>

#define Bn 64
#define Tn 50
#define Pn 49
#define En 512
#define Hn 512
#define Vn 10000
#define IEn 1024
#define G5 2560   // 5*H

typedef __attribute__((ext_vector_type(8))) short bf16x8;
typedef __attribute__((ext_vector_type(4))) float f32x4;

__device__ __forceinline__ float sigm(float x)  { return 1.0f / (1.0f + __expf(-x)); }
__device__ __forceinline__ float tanh_f(float x){ return 1.0f - 2.0f / (1.0f + __expf(2.0f * x)); }

__device__ __forceinline__ unsigned short f2b(float f) {
    union { float f; unsigned int u; } c; c.f = f;
    unsigned int u = c.u;
    u += 0x7fffu + ((u >> 16) & 1u);   // RNE (finite values only)
    return (unsigned short)(u >> 16);
}
__device__ __forceinline__ float b2f(unsigned short u) {
    union { unsigned int u; float f; } c; c.u = ((unsigned int)u) << 16;
    return c.f;
}

// ---------------------------------------------------------------------------
// fp32 tiled GEMM (kept for small ops): C[M,N] = A[M,K] @ B[K,N] (+bias)(+rowadd)
// gridDim.z > 1 => split-K partial mode.
// ---------------------------------------------------------------------------
template<bool GATHER>
__global__ __launch_bounds__(256)
void gemm64(const float* __restrict__ A, int lda,
            const float* __restrict__ B,
            float* __restrict__ C,
            int M, int N, int K,
            const float* __restrict__ bias,
            const float* __restrict__ rowadd, int rowDiv, long rowStride,
            const int* __restrict__ gidx)
{
    const int n0 = blockIdx.x * 64;
    const int m0 = blockIdx.y * 64;
    const long koff = (long)blockIdx.z * K;
    const float* Bp = B + koff * N;
    float* Cp = C + (gridDim.z > 1 ? (size_t)blockIdx.z * (size_t)M * (size_t)N : (size_t)0);

    __shared__ float As[16][64];
    __shared__ float Bs[16][64];

    const int tid = threadIdx.x;
    const int tx = tid & 15;
    const int ty = tid >> 4;
    const int ra = tid >> 2;
    const int ca = (tid & 3) << 2;

    long arow = GATHER ? (long)gidx[m0 + ra] : (long)(m0 + ra);
    const float* Arow = A + arow * (long)lda + koff + ca;

    const int kl = ty;
    const int nb = tx << 2;
    const int ncol = n0 + nb;

    float acc[4][4] = {{0.f,0.f,0.f,0.f},{0.f,0.f,0.f,0.f},{0.f,0.f,0.f,0.f},{0.f,0.f,0.f,0.f}};

    for (int k0 = 0; k0 < K; k0 += 16) {
        float4 av = *(const float4*)(Arow + k0);
        float4 bv;
        const float* bptr = Bp + (long)(k0 + kl) * N + ncol;
        if (ncol + 3 < N) {
            bv = *(const float4*)bptr;
        } else {
            bv.x = (ncol + 0 < N) ? bptr[0] : 0.f;
            bv.y = (ncol + 1 < N) ? bptr[1] : 0.f;
            bv.z = (ncol + 2 < N) ? bptr[2] : 0.f;
            bv.w = (ncol + 3 < N) ? bptr[3] : 0.f;
        }
        __syncthreads();
        As[ca + 0][ra] = av.x; As[ca + 1][ra] = av.y;
        As[ca + 2][ra] = av.z; As[ca + 3][ra] = av.w;
        *(float4*)&Bs[kl][nb] = bv;
        __syncthreads();
        #pragma unroll
        for (int kk = 0; kk < 16; kk++) {
            const float4 a = *(const float4*)&As[kk][ty << 2];
            const float4 b = *(const float4*)&Bs[kk][tx << 2];
            const float a_[4] = {a.x, a.y, a.z, a.w};
            const float b_[4] = {b.x, b.y, b.z, b.w};
            #pragma unroll
            for (int i = 0; i < 4; i++)
                #pragma unroll
                for (int j = 0; j < 4; j++)
                    acc[i][j] = fmaf(a_[i], b_[j], acc[i][j]);
        }
    }

    #pragma unroll
    for (int i = 0; i < 4; i++) {
        const int rr = m0 + (ty << 2) + i;
        #pragma unroll
        for (int j = 0; j < 4; j++) {
            const int cc = n0 + (tx << 2) + j;
            if (cc < N) {
                float v = acc[i][j];
                if (bias)   v += bias[cc];
                if (rowadd) v += rowadd[(long)(rr / rowDiv) * rowStride + cc];
                Cp[(long)rr * N + cc] = v;
            }
        }
    }
}

// ---------------------------------------------------------------------------
// bf16 MFMA GEMM: C[M,N] = A_bf[M,K] @ BT_bf[N,K]^T, fp32 accum.
// 128x128 tile, BK=32, 4 waves (2x2), each wave 64x64 via 4x4 frags of 16x16x32.
// LDS row stride 40 bf16 (80B): uniform bank spread for ds_*_b128.
// ---------------------------------------------------------------------------
template<int OUTF, int OUTB>
__global__ __launch_bounds__(256)
void gemm_mfma(const unsigned short* __restrict__ A,
               const unsigned short* __restrict__ BT,
               float* __restrict__ Cf, unsigned short* __restrict__ Cb,
               int M, int N, int K,
               const float* __restrict__ bias,
               const float* __restrict__ rowadd, int rowDiv)
{
    __shared__ __align__(16) unsigned short Asm[128][40];
    __shared__ __align__(16) unsigned short Bsm[128][40];

    const int tid = threadIdx.x;
    const int lane = tid & 63;
    const int wid = tid >> 6;
    const int wm = wid >> 1;
    const int wn = wid & 1;
    const int m0 = blockIdx.y * 128;
    const int n0 = blockIdx.x * 128;

    const int r0 = tid >> 2;      // staging row (and +64)
    const int kg = tid & 3;       // staging k-group of 8 bf16

    const int ar0 = m0 + r0, ar1 = m0 + r0 + 64;
    const int br0 = n0 + r0, br1 = n0 + r0 + 64;

    f32x4 acc[4][4] = {};
    const uint4 zero4 = {0u, 0u, 0u, 0u};

    uint4 a0, a1, b0, b1;
    {
        const long ka = (long)kg * 8;
        a0 = (ar0 < M) ? *(const uint4*)(A + (long)ar0 * K + ka) : zero4;
        a1 = (ar1 < M) ? *(const uint4*)(A + (long)ar1 * K + ka) : zero4;
        b0 = (br0 < N) ? *(const uint4*)(BT + (long)br0 * K + ka) : zero4;
        b1 = (br1 < N) ? *(const uint4*)(BT + (long)br1 * K + ka) : zero4;
    }

    for (int k0 = 0; k0 < K; k0 += 32) {
        __syncthreads();
        *(uint4*)&Asm[r0     ][kg * 8] = a0;
        *(uint4*)&Asm[r0 + 64][kg * 8] = a1;
        *(uint4*)&Bsm[r0     ][kg * 8] = b0;
        *(uint4*)&Bsm[r0 + 64][kg * 8] = b1;
        __syncthreads();

        if (k0 + 32 < K) {
            const long ka = (long)(k0 + 32) + kg * 8;
            a0 = (ar0 < M) ? *(const uint4*)(A + (long)ar0 * K + ka) : zero4;
            a1 = (ar1 < M) ? *(const uint4*)(A + (long)ar1 * K + ka) : zero4;
            b0 = (br0 < N) ? *(const uint4*)(BT + (long)br0 * K + ka) : zero4;
            b1 = (br1 < N) ? *(const uint4*)(BT + (long)br1 * K + ka) : zero4;
        }

        bf16x8 af[4], bfr[4];
        const int arow = wm * 64 + (lane & 15);
        const int brow = wn * 64 + (lane & 15);
        const int kcol = (lane >> 4) * 8;
        #pragma unroll
        for (int i = 0; i < 4; i++) {
            af[i]  = *(const bf16x8*)&Asm[arow + i * 16][kcol];
            bfr[i] = *(const bf16x8*)&Bsm[brow + i * 16][kcol];
        }
        #pragma unroll
        for (int mi = 0; mi < 4; mi++)
            #pragma unroll
            for (int ni = 0; ni < 4; ni++)
                acc[mi][ni] = __builtin_amdgcn_mfma_f32_16x16x32_bf16(af[mi], bfr[ni], acc[mi][ni], 0, 0, 0);
    }

    const int crow = m0 + wm * 64 + (lane >> 4) * 4;
    const int ccol0 = n0 + wn * 64 + (lane & 15);
    #pragma unroll
    for (int ni = 0; ni < 4; ni++) {
        const int col = ccol0 + ni * 16;
        if (col >= N) continue;
        const float bvv = bias ? bias[col] : 0.f;
        #pragma unroll
        for (int mi = 0; mi < 4; mi++) {
            #pragma unroll
            for (int r = 0; r < 4; r++) {
                const int rr = crow + mi * 16 + r;
                if (rr < M) {
                    float v = acc[mi][ni][r] + bvv;
                    if (rowadd) v += rowadd[(long)(rr / rowDiv) * N + col];
                    if (OUTF) Cf[(long)rr * N + col] = v;
                    if (OUTB) Cb[(long)rr * N + col] = f2b(v);
                }
            }
        }
    }
}

// out[n][k] = bf16(in[k][n]); in row stride = istride
__global__ __launch_bounds__(256)
void transpose_bf16(const float* __restrict__ in, unsigned short* __restrict__ out,
                    int K, int N, int istride)
{
    __shared__ float tile[32][33];
    const int k0 = blockIdx.y * 32;
    const int n0 = blockIdx.x * 32;
    const int tx = threadIdx.x & 31, ty = threadIdx.x >> 5;
    #pragma unroll
    for (int j = 0; j < 4; j++) {
        int k = k0 + ty + j * 8, n = n0 + tx;
        tile[ty + j * 8][tx] = (k < K && n < N) ? in[(long)k * istride + n] : 0.f;
    }
    __syncthreads();
    #pragma unroll
    for (int j = 0; j < 4; j++) {
        int n = n0 + ty + j * 8, k = k0 + tx;
        if (n < N && k < K) out[(long)n * K + k] = f2b(tile[tx][ty + j * 8]);
    }
}

__global__ void convert_bf16(const float* __restrict__ in, unsigned short* __restrict__ out, int n4)
{
    int i = blockIdx.x * 256 + threadIdx.x;
    if (i < n4) {
        float4 v = ((const float4*)in)[i];
        ushort4 u;
        u.x = f2b(v.x); u.y = f2b(v.y); u.z = f2b(v.z); u.w = f2b(v.w);
        ((ushort4*)out)[i] = u;
    }
}

// WE_bf[r][:] = bf16(emb[w[r]][:])   r in [0,3200), 128 threads x float4
__global__ void gather_convert(const float* __restrict__ emb, const int* __restrict__ w,
                               unsigned short* __restrict__ out)
{
    const int r = blockIdx.x;
    const long row = w[r];
    const float4 v = ((const float4*)(emb + row * 512))[threadIdx.x];
    ushort4 u;
    u.x = f2b(v.x); u.y = f2b(v.y); u.z = f2b(v.z); u.w = f2b(v.w);
    ((ushort4*)(out + (long)r * 512))[threadIdx.x] = u;
}

// vg[b,e] = mean_p vproj_bf[b,p,e]
__global__ void vg_mean(const unsigned short* __restrict__ vproj, float* __restrict__ vg)
{
    const int tid = blockIdx.x * 256 + threadIdx.x;
    const int b = tid >> 9, e = tid & 511;
    const unsigned short* p = vproj + (long)b * Pn * En + e;
    float s = 0.f;
    #pragma unroll 7
    for (int q = 0; q < Pn; q++) s += b2f(p[q * En]);
    vg[tid] = s * (1.0f / 49.0f);
}

__global__ void h0m0(const float* __restrict__ vg,
                     const float* __restrict__ Wh, const float* __restrict__ bh,
                     const float* __restrict__ Wm, const float* __restrict__ bm,
                     float* __restrict__ h, float* __restrict__ m)
{
    __shared__ float vgs[512];
    const int b = blockIdx.x, e = threadIdx.x;
    vgs[e] = vg[b * 512 + e];
    __syncthreads();
    float a1 = bh[e], a2 = bm[e];
    #pragma unroll 8
    for (int k = 0; k < 512; k++) {
        const float x = vgs[k];
        a1 = fmaf(x, Wh[(long)k * 512 + e], a1);
        a2 = fmaf(x, Wm[(long)k * 512 + e], a2);
    }
    h[b * 512 + e] = a1;
    m[b * 512 + e] = a2;
}

// LSTM elementwise update; also emits bf16 copies of h_t, s_t rows.
__global__ void lstm_update(const float* __restrict__ part,
                            const float* __restrict__ base,
                            float* __restrict__ h, float* __restrict__ m,
                            float* __restrict__ Hs, float* __restrict__ Ss,
                            unsigned short* __restrict__ Hb, unsigned short* __restrict__ Sb,
                            int t)
{
    const int tid = blockIdx.x * blockDim.x + threadIdx.x;
    const int b = tid >> 9, e = tid & 511;
    const long r = (long)b * Tn + t;
    const float* bs = base + r * G5;
    float gi = bs[e], gf = bs[512 + e], go = bs[1024 + e], gg = bs[1536 + e], g5 = bs[2048 + e];
    const float* pp = part + (long)b * G5;
    #pragma unroll
    for (int s = 0; s < 4; s++) {
        const float* q = pp + (long)s * Bn * G5;
        gi += q[e]; gf += q[512 + e]; go += q[1024 + e]; gg += q[1536 + e]; g5 += q[2048 + e];
    }
    const float i = sigm(gi), f = sigm(gf), o = sigm(go);
    const float mn = fmaf(i, tanh_f(g5), f * m[tid]);
    const float tm = tanh_f(mn);
    const float hh = o * tm;
    const float ss = gg * tm;
    m[tid] = mn;
    h[tid] = hh;
    Hs[r * 512 + e] = hh;
    Ss[r * 512 + e] = ss;
    Hb[r * 512 + e] = f2b(hh);
    Sb[r * 512 + e] = f2b(ss);
}

// Per-(b,t) adaptive attention; vproj is bf16; writes CH as bf16.
__global__ __launch_bounds__(256)
void attn(const unsigned short* __restrict__ vproj, const float* __restrict__ pv,
          const float* __restrict__ PH, const float* __restrict__ PS,
          const float* __restrict__ Hs, const float* __restrict__ Waz,
          const float* __restrict__ baz, unsigned short* __restrict__ CHb)
{
    const int r = blockIdx.x;
    const int b = r / Tn;
    const int tid = threadIdx.x;
    const int lane = tid & 63, wid = tid >> 6;

    __shared__ float ps_s[512];
    __shared__ float ph_s[512];
    __shared__ float alog[64];

    for (int i = tid; i < 512; i += 256) {
        ps_s[i] = PS[(long)r * 512 + i];
        ph_s[i] = PH[(long)r * 512 + i];
    }
    __syncthreads();

    const float4 wz0 = *(const float4*)(Waz + lane * 8);
    const float4 wz1 = *(const float4*)(Waz + lane * 8 + 4);
    const float4 q0  = *(const float4*)&ps_s[lane * 8];
    const float4 q1  = *(const float4*)&ps_s[lane * 8 + 4];

    for (int slot = wid; slot < Pn + 1; slot += 4) {
        const float* src = (slot < Pn) ? (pv + ((long)b * Pn + slot) * 512)
                                       : (const float*)ph_s;
        const float4 x0 = *(const float4*)(src + lane * 8);
        const float4 x1 = *(const float4*)(src + lane * 8 + 4);
        float d = 0.f;
        d = fmaf(tanh_f(x0.x + q0.x), wz0.x, d);
        d = fmaf(tanh_f(x0.y + q0.y), wz0.y, d);
        d = fmaf(tanh_f(x0.z + q0.z), wz0.z, d);
        d = fmaf(tanh_f(x0.w + q0.w), wz0.w, d);
        d = fmaf(tanh_f(x1.x + q1.x), wz1.x, d);
        d = fmaf(tanh_f(x1.y + q1.y), wz1.y, d);
        d = fmaf(tanh_f(x1.z + q1.z), wz1.z, d);
        d = fmaf(tanh_f(x1.w + q1.w), wz1.w, d);
        #pragma unroll
        for (int s = 32; s >= 1; s >>= 1) d += __shfl_xor(d, s);
        if (lane == 0) alog[slot] = d + baz[0];
    }
    __syncthreads();

    if (wid == 0) {
        const float v = (lane < Pn + 1) ? alog[lane] : -3.4e38f;
        float mx = v;
        #pragma unroll
        for (int s = 32; s >= 1; s >>= 1) mx = fmaxf(mx, __shfl_xor(mx, s));
        const float ev = (lane < Pn + 1) ? __expf(v - mx) : 0.f;
        float sm = ev;
        #pragma unroll
        for (int s = 32; s >= 1; s >>= 1) sm += __shfl_xor(sm, s);
        if (lane < Pn + 1) alog[lane] = ev / sm;
    }
    __syncthreads();

    const float a49 = alog[Pn];
    for (int e = tid; e < 512; e += 256) {
        const float hval = Hs[(long)r * 512 + e];
        float c = a49 * hval;
        const unsigned short* vp = vproj + (long)b * Pn * 512 + e;
        #pragma unroll 7
        for (int q = 0; q < Pn; q++) c = fmaf(alog[q], b2f(vp[q * 512]), c);
        CHb[(long)r * 512 + e] = f2b(c + hval);
    }
}

__global__ __launch_bounds__(256)
void softmax_mask(float* __restrict__ out, const int* __restrict__ lengths)
{
    const int r = blockIdx.x, b = r / Tn, t = r % Tn;
    float* row = out + (long)r * Vn;
    const int tid = threadIdx.x;
    float4* row4 = (float4*)row;

    if (t >= lengths[b]) {
        const float4 z = {0.f, 0.f, 0.f, 0.f};
        for (int i = tid; i < Vn / 4; i += 256) row4[i] = z;
        return;
    }

    __shared__ float red[4];
    const int lane = tid & 63, wid = tid >> 6;

    float mx = -3.4e38f;
    for (int i = tid; i < Vn / 4; i += 256) {
        const float4 v = row4[i];
        mx = fmaxf(mx, fmaxf(fmaxf(v.x, v.y), fmaxf(v.z, v.w)));
    }
    #pragma unroll
    for (int s = 32; s >= 1; s >>= 1) mx = fmaxf(mx, __shfl_xor(mx, s));
    if (lane == 0) red[wid] = mx;
    __syncthreads();
    mx = fmaxf(fmaxf(red[0], red[1]), fmaxf(red[2], red[3]));

    float sm = 0.f;
    for (int i = tid; i < Vn / 4; i += 256) {
        const float4 v = row4[i];
        sm += __expf(v.x - mx) + __expf(v.y - mx) + __expf(v.z - mx) + __expf(v.w - mx);
    }
    #pragma unroll
    for (int s = 32; s >= 1; s >>= 1) sm += __shfl_xor(sm, s);
    __syncthreads();
    if (lane == 0) red[wid] = sm;
    __syncthreads();
    sm = red[0] + red[1] + red[2] + red[3];
    const float inv = 1.0f / sm;

    for (int i = tid; i < Vn / 4; i += 256) {
        float4 v = row4[i];
        v.x = __expf(v.x - mx) * inv;
        v.y = __expf(v.y - mx) * inv;
        v.z = __expf(v.z - mx) * inv;
        v.w = __expf(v.w - mx) * inv;
        row4[i] = v;
    }
}

extern "C" void kernel_launch(void* const* d_in, const int* in_sizes, int n_in,
                              void* d_out, int out_size, void* d_ws, size_t ws_size,
                              hipStream_t stream)
{
    (void)in_sizes; (void)n_in; (void)out_size; (void)ws_size;
    const float* v   = (const float*)d_in[0];
    const int*   w   = (const int*)  d_in[1];
    const int*   len = (const int*)  d_in[2];
    const float* emb = (const float*)d_in[3];
    const float* Wv  = (const float*)d_in[4];
    const float* bv  = (const float*)d_in[5];
    const float* Wh  = (const float*)d_in[6];
    const float* bh  = (const float*)d_in[7];
    const float* Wm  = (const float*)d_in[8];
    const float* bm  = (const float*)d_in[9];
    const float* Wl  = (const float*)d_in[10];
    const float* bl  = (const float*)d_in[11];
    const float* Wav = (const float*)d_in[12];
    const float* bav = (const float*)d_in[13];
    const float* Wah = (const float*)d_in[14];
    const float* bah = (const float*)d_in[15];
    const float* Was = (const float*)d_in[16];
    const float* bas = (const float*)d_in[17];
    const float* Waz = (const float*)d_in[18];
    const float* baz = (const float*)d_in[19];
    const float* Wp  = (const float*)d_in[20];
    const float* bp  = (const float*)d_in[21];
    float* out_f = (float*)d_out;

    // ---- workspace carve (≈26 MB; previous rounds proved ≥49 MB available) ----
    char* wsp = (char*)d_ws;
    size_t off = 0;
    auto walloc = [&](size_t bytes) -> void* {
        void* r = wsp + off;
        off += (bytes + 255) & ~(size_t)255;
        return r;
    };
    unsigned short* WpT    = (unsigned short*)walloc((size_t)Vn * 512 * 2);
    unsigned short* WvT    = (unsigned short*)walloc((size_t)512 * 1024 * 2);
    unsigned short* WlT0   = (unsigned short*)walloc((size_t)G5 * 512 * 2);
    unsigned short* WavT   = (unsigned short*)walloc((size_t)512 * 512 * 2);
    unsigned short* WahT   = (unsigned short*)walloc((size_t)512 * 512 * 2);
    unsigned short* WasT   = (unsigned short*)walloc((size_t)512 * 512 * 2);
    unsigned short* vprojb = (unsigned short*)walloc((size_t)3136 * 512 * 2);
    unsigned short* CHb    = (unsigned short*)walloc((size_t)3200 * 512 * 2);
    float* vg   = (float*)walloc((size_t)64 * 512 * 4);
    float* hbuf = (float*)walloc((size_t)64 * 512 * 4);
    float* mbuf = (float*)walloc((size_t)64 * 512 * 4);
    float* vgw  = (float*)walloc((size_t)64 * G5 * 4);
    float* part = (float*)walloc((size_t)4 * 64 * G5 * 4);

    // ---- scratch in dead upper region of d_out (base uses floats [0, 8.192M);
    //      everything here is dead before the logits GEMM overwrites d_out) ----
    char* sp = (char*)(out_f + (size_t)3200 * G5);
    size_t off2 = 0;
    auto salloc = [&](size_t bytes) -> void* {
        void* r = sp + off2;
        off2 += (bytes + 255) & ~(size_t)255;
        return r;
    };
    unsigned short* vB  = (unsigned short*)salloc((size_t)3136 * 1024 * 2);
    unsigned short* WEb = (unsigned short*)salloc((size_t)3200 * 512 * 2);
    float* pvb = (float*)salloc((size_t)3136 * 512 * 4);
    float* Hs  = (float*)salloc((size_t)3200 * 512 * 4);
    float* Ss  = (float*)salloc((size_t)3200 * 512 * 4);
    unsigned short* Hsb = (unsigned short*)salloc((size_t)3200 * 512 * 2);
    unsigned short* Ssb = (unsigned short*)salloc((size_t)3200 * 512 * 2);
    float* PHb = (float*)salloc((size_t)3200 * 512 * 4);
    float* PSb = (float*)salloc((size_t)3200 * 512 * 4);

    // ---- weight transposes / input conversions to bf16 ----
    transpose_bf16<<<dim3(512/32, 1024/32), 256, 0, stream>>>(Wv, WvT, 1024, 512, 512);
    transpose_bf16<<<dim3(G5/32, 512/32), 256, 0, stream>>>(Wl, WlT0, 512, G5, G5);
    transpose_bf16<<<dim3(16, 16), 256, 0, stream>>>(Wav, WavT, 512, 512, 512);
    transpose_bf16<<<dim3(16, 16), 256, 0, stream>>>(Wah, WahT, 512, 512, 512);
    transpose_bf16<<<dim3(16, 16), 256, 0, stream>>>(Was, WasT, 512, 512, 512);
    transpose_bf16<<<dim3((Vn + 31)/32, 16), 256, 0, stream>>>(Wp, WpT, 512, Vn, Vn);
    convert_bf16<<<(3136*1024/4 + 255)/256, 256, 0, stream>>>(v, vB, 3136*1024/4);
    gather_convert<<<3200, 128, 0, stream>>>(emb, w, WEb);

    // 1. vproj(bf16) = v @ Wv + bv
    gemm_mfma<0,1><<<dim3(4, 25), 256, 0, stream>>>(vB, WvT, nullptr, vprojb,
                                                    3136, 512, 1024, bv, nullptr, 1);
    // 2. vg ; 3. h0,m0
    vg_mean<<<128, 256, 0, stream>>>(vprojb, vg);
    h0m0<<<64, 512, 0, stream>>>(vg, Wh, bh, Wm, bm, hbuf, mbuf);
    // 4. vgw = vg @ Wl[512:1024] + bl   (small, fp32)
    gemm64<false><<<dim3(40, 1, 1), 256, 0, stream>>>(vg, 512, Wl + (size_t)512 * G5, vgw,
                                                      64, G5, 512, bl, nullptr, 1, 0, nullptr);
    // 5. pv = vproj @ Wav + bav
    gemm_mfma<1,0><<<dim3(4, 25), 256, 0, stream>>>(vprojb, WavT, pvb, nullptr,
                                                    3136, 512, 512, bav, nullptr, 1);
    // 6. base = we @ Wl[0:512] + vgw[b]  -> d_out (dead before logits)
    gemm_mfma<1,0><<<dim3(20, 25), 256, 0, stream>>>(WEb, WlT0, out_f, nullptr,
                                                     3200, G5, 512, nullptr, vgw, Tn);
    // 7. sequential scan (fp32 recurrence)
    for (int t = 0; t < Tn; t++) {
        gemm64<false><<<dim3(40, 1, 4), 256, 0, stream>>>(hbuf, 512, Wl + (size_t)1024 * G5, part,
                                                          64, G5, 128, nullptr, nullptr, 1, 0, nullptr);
        lstm_update<<<64, 512, 0, stream>>>(part, out_f, hbuf, mbuf, Hs, Ss, Hsb, Ssb, t);
    }
    // 8. PH, PS
    gemm_mfma<1,0><<<dim3(4, 25), 256, 0, stream>>>(Hsb, WahT, PHb, nullptr,
                                                    3200, 512, 512, bah, nullptr, 1);
    gemm_mfma<1,0><<<dim3(4, 25), 256, 0, stream>>>(Ssb, WasT, PSb, nullptr,
                                                    3200, 512, 512, bas, nullptr, 1);
    // 9. attention -> CH (bf16)
    attn<<<3200, 256, 0, stream>>>(vprojb, pvb, PHb, PSb, Hs, Waz, baz, CHb);
    // 10. logits = CH @ Wp + bp -> d_out
    gemm_mfma<1,0><<<dim3(79, 25), 256, 0, stream>>>(CHb, WpT, out_f, nullptr,
                                                     3200, Vn, 512, bp, nullptr, 1);
    // 11. softmax + mask
    softmax_mask<<<3200, 256, 0, stream>>>(out_f, len);
}